// Round 13
// baseline (92.523 us; speedup 1.0000x reference)
//
#include <hip/hip_runtime.h>
#include <hip/hip_bf16.h>

#define N_X    65536
#define N_IND  1024
#define N_DESC 64
#define TILES  (N_IND / 16)       // 64 MFMA row-tiles (full z-panel)
#define REPS   8                  // DIAGNOSTIC: 8x loop replication for rocprof
#define L2E    1.4426950408889634f
#define L2E2   2.8853900817779268f
#define SKIP_THR (-60.0f)         // 2^-60 * 1024 * |alpha| ~ 4e-15 << tol

typedef __attribute__((ext_vector_type(8))) short  short8;
typedef __attribute__((ext_vector_type(4))) float  f32x4;
typedef __attribute__((ext_vector_type(2))) float  f32x2;

static __device__ __forceinline__ ushort f2bf(float f) {
    union { float f; unsigned u; } a; a.f = f;
    unsigned r = a.u + 0x7FFF + ((a.u >> 16) & 1);   // RNE to bf16
    return (ushort)(r >> 16);
}
static __device__ __forceinline__ float bf2f(ushort h) {
    union { unsigned u; float f; } a; a.u = (unsigned)h << 16;
    return a.f;
}

// ---------------------------------------------------------------------------
// Round 13 = Round 12 kernel (best, 24.6 us) with the inner tile-loop
// replicated REPS=8x for rocprof visibility (the kernel is otherwise
// invisible below the harness's 40 us poison-fill dispatches).
//  - rep 0 accumulates with scale=1 (real result, unchanged output);
//  - reps 1..7 use scale=0 made OPAQUE via asm (no folding, no DCE);
//  - asm "memory" between reps blocks cross-rep CSE of LDS reads.
// L (true loop time) = (dur_r13 - dur_r12) / 7; counters during this run
// are dominated by the real loop's instruction mix.
// ---------------------------------------------------------------------------
__global__ __launch_bounds__(1024) void igpr_fused(
        const float* __restrict__ x, const float* __restrict__ z,
        const float* __restrict__ alpha, const float* __restrict__ ls,
        float* __restrict__ out) {
    struct SM {
        uint4 zt[N_IND * 8];   // 1024 rows * 128 B = 128 KB (swizzled)
        float z2[N_IND];       // log2e * ||zw_i||^2
        float al[N_IND];       // alpha
        float wls[N_DESC];     // exp(-ls/2)
    };
    __shared__ SM sm;          // 136.25 KB of the CU's 160 KB

    const int tid  = threadIdx.x;
    const int lane = tid & 63;
    const int wave = tid >> 6;
    const int p = lane & 15;          // x-col within strip / D col
    const int g = lane >> 4;          // k-group; D rows 4g..4g+3 (z-rows)
    const int j = blockIdx.x * 256 + wave * 16 + p;   // this lane's x column

    if (tid < N_DESC) sm.wls[tid] = __expf(-0.5f * ls[tid]);
    __syncthreads();   // wls ready

    // ---- stage full z-panel into LDS (f32 -> weighted bf16, swizzled) ----
    {
        char* zb = reinterpret_cast<char*>(sm.zt);
#pragma unroll
        for (int rb = 0; rb < 8; ++rb) {
            int lb  = rb * 1024 + tid;       // 16B-output-granule index
            int row = lb >> 3, gr = lb & 7;  // z-row, granule in row
            float4 v0 = *reinterpret_cast<const float4*>(&z[row * 64 + gr * 8]);
            float4 v1 = *reinterpret_cast<const float4*>(&z[row * 64 + gr * 8 + 4]);
            float vv[8] = {v0.x, v0.y, v0.z, v0.w, v1.x, v1.y, v1.z, v1.w};
            ushort hb[8];
            float sq = 0.f;
#pragma unroll
            for (int e = 0; e < 8; ++e) {
                ushort h = f2bf(vv[e] * sm.wls[gr * 8 + e]);
                hb[e] = h;
                float vr = bf2f(h);
                sq = fmaf(vr, vr, sq);
            }
            uint4 u = make_uint4(
                (unsigned)hb[0] | ((unsigned)hb[1] << 16),
                (unsigned)hb[2] | ((unsigned)hb[3] << 16),
                (unsigned)hb[4] | ((unsigned)hb[5] << 16),
                (unsigned)hb[6] | ((unsigned)hb[7] << 16));
            int sw = row * 128 + ((gr * 16) ^ ((row & 7) << 4));
            *reinterpret_cast<uint4*>(zb + sw) = u;
            // row-sum over the 8 granule-lanes (xor partners within wave)
            sq += __shfl_xor(sq, 1);
            sq += __shfl_xor(sq, 2);
            sq += __shfl_xor(sq, 4);
            if (gr == 0) sm.z2[row] = sq * L2E;
        }
        sm.al[tid] = alpha[tid];   // N_IND == blockDim.x
    }

    // ---- B fragment (one 16-col strip) + log2e*x_sq, overlaps staging ----
    short8 b0, b1;
    float xs2;
    {
        const float* xr = x + (size_t)j * N_DESC;
        float sq = 0.f;
        short8 bb[2];
#pragma unroll
        for (int h = 0; h < 2; ++h) {
            float4 v0 = *reinterpret_cast<const float4*>(xr + h * 32 + g * 8);
            float4 v1 = *reinterpret_cast<const float4*>(xr + h * 32 + g * 8 + 4);
            float vv[8] = {v0.x, v0.y, v0.z, v0.w, v1.x, v1.y, v1.z, v1.w};
#pragma unroll
            for (int e = 0; e < 8; ++e) {
                ushort hh = f2bf(vv[e] * sm.wls[h * 32 + g * 8 + e]);
                bb[h][e] = (short)hh;
                float xv = bf2f(hh);
                sq = fmaf(xv, xv, sq);
            }
        }
        b0 = bb[0]; b1 = bb[1];
        sq += __shfl_xor(sq, 16);
        sq += __shfl_xor(sq, 32);
        xs2 = sq * L2E;
    }

    __syncthreads();   // z-panel ready (LDS read-only from here)

    const char* zb = reinterpret_cast<const char*>(sm.zt);
    const int rb0 = p * 128 + ((16 * g)      ^ ((p & 7) << 4));
    const int rb1 = p * 128 + ((64 + 16 * g) ^ ((p & 7) << 4));

    f32x2 accJ = {0.f, 0.f};
    const f32x2 xs2p = {xs2, xs2};

#pragma unroll 1
    for (int rep = 0; rep < REPS; ++rep) {
        float scale = (rep == 0) ? 1.0f : 0.0f;
        asm volatile("" : "+v"(scale));     // opaque: no fold, no DCE
        asm volatile("" ::: "memory");      // no cross-rep CSE of LDS reads
        const f32x2 sc2 = {scale, scale};

#pragma unroll 2
        for (int it = 0; it < TILES; ++it) {
            short8 a0 = *reinterpret_cast<const short8*>(zb + it * 2048 + rb0);
            short8 a1 = *reinterpret_cast<const short8*>(zb + it * 2048 + rb1);
            float4 z2 = *reinterpret_cast<const float4*>(&sm.z2[it * 16 + g * 4]);

            f32x4 t = {0.f, 0.f, 0.f, 0.f};
            t = __builtin_amdgcn_mfma_f32_16x16x32_bf16(a0, b0, t, 0, 0, 0);
            t = __builtin_amdgcn_mfma_f32_16x16x32_bf16(a1, b1, t, 0, 0, 0);

            f32x2 z2p0 = {z2.x, z2.y}, z2p1 = {z2.z, z2.w};
            f32x2 d0 = {t[0], t[1]}, d1 = {t[2], t[3]};
            f32x2 arg0 = d0 * L2E2 - (z2p0 + xs2p);    // pk_fma / pk_add
            f32x2 arg1 = d1 * L2E2 - (z2p1 + xs2p);
            float m = fmaxf(fmaxf(arg0.x, arg0.y), fmaxf(arg1.x, arg1.y));

            if (!__all(m < SKIP_THR)) {
                float4 a4 = *reinterpret_cast<const float4*>(&sm.al[it * 16 + g * 4]);
                f32x2 pv0 = {__builtin_amdgcn_exp2f(arg0.x),
                             __builtin_amdgcn_exp2f(arg0.y)};
                f32x2 pv1 = {__builtin_amdgcn_exp2f(arg1.x),
                             __builtin_amdgcn_exp2f(arg1.y)};
                f32x2 a4p0 = {a4.x, a4.y}, a4p1 = {a4.z, a4.w};
                accJ = accJ + (a4p0 * pv0) * sc2;
                accJ = accJ + (a4p1 * pv1) * sc2;
            }
        }
    }

    float r = accJ.x + accJ.y;
    r += __shfl_xor(r, 16);
    r += __shfl_xor(r, 32);
    if (g == 0) out[j] = r;
}

extern "C" void kernel_launch(void* const* d_in, const int* in_sizes, int n_in,
                              void* d_out, int out_size, void* d_ws, size_t ws_size,
                              hipStream_t stream) {
    const float* x     = (const float*)d_in[0];   // (65536, 64)
    const float* z     = (const float*)d_in[1];   // (1024, 64)
    const float* alpha = (const float*)d_in[2];   // (1024,)
    const float* ls    = (const float*)d_in[3];   // (64,)
    float* out = (float*)d_out;                   // (65536, 1)

    igpr_fused<<<dim3(N_X / 256), dim3(1024), 0, stream>>>(x, z, alpha, ls, out);
}

// Round 14
// 22.036 us; speedup vs baseline: 4.1987x; 4.1987x over previous
//
#include <hip/hip_runtime.h>
#include <hip/hip_bf16.h>

#define N_X    65536
#define N_IND  1024
#define N_DESC 64
#define TILES  (N_IND / 16)       // 64 MFMA row-tiles (full z-panel)
#define L2E    1.4426950408889634f
#define L2E2   2.8853900817779268f
#define SKIP_THR (-60.0f)         // 2^-60 * 1024 * |alpha| ~ 4e-15 << tol

typedef __attribute__((ext_vector_type(8))) short  short8;
typedef __attribute__((ext_vector_type(4))) float  f32x4;
typedef __attribute__((ext_vector_type(2))) float  f32x2;

static __device__ __forceinline__ ushort f2bf(float f) {
    union { float f; unsigned u; } a; a.f = f;
    unsigned r = a.u + 0x7FFF + ((a.u >> 16) & 1);   // RNE to bf16
    return (ushort)(r >> 16);
}
static __device__ __forceinline__ float bf2f(ushort h) {
    union { unsigned u; float f; } a; a.u = (unsigned)h << 16;
    return a.f;
}

// ---------------------------------------------------------------------------
// Round 14 = R12 loop (proven: loop ~11 us incl. exp-skip) + staged-latency
// fixes identified by the R13 rep-scaled profile (staging+prologue ~9-11 us):
//  (1) x loads issued FIRST -> in flight under the whole z-staging phase;
//  (2) z staging explicitly 2-deep pipelined (named rotating reg pairs,
//      rule #20) -> granule rb+1's loads overlap granule rb's convert+write;
//  (3) wls LDS array + its barrier removed: each thread computes its 24
//      weights (8 staging cols = (tid&7)*8.., 16 x-frag cols) via __expf.
// Loop, swizzle, skip-test, tail identical to R12.
// Swizzle: byte colb ^= (row&7)<<4 on BOTH write and read (rule #21).
// C/D: col = lane&15 (x-col), row = 4*(lane>>4)+reg (z-row).
// ---------------------------------------------------------------------------
__global__ __launch_bounds__(1024) void igpr_fused(
        const float* __restrict__ x, const float* __restrict__ z,
        const float* __restrict__ alpha, const float* __restrict__ ls,
        float* __restrict__ out) {
    struct SM {
        uint4 zt[N_IND * 8];   // 1024 rows * 128 B = 128 KB (swizzled)
        float z2[N_IND];       // log2e * ||zw_i||^2
        float al[N_IND];       // alpha
    };
    __shared__ SM sm;          // 136 KB of the CU's 160 KB

    const int tid  = threadIdx.x;
    const int lane = tid & 63;
    const int wave = tid >> 6;
    const int p = lane & 15;          // x-col within strip / D col
    const int g = lane >> 4;          // k-group; D rows 4g..4g+3 (z-rows)
    const int j = blockIdx.x * 256 + wave * 16 + p;   // this lane's x column

    // ---- (1) issue x loads immediately; consumed after z staging ----
    const float* xr = x + (size_t)j * N_DESC;
    float4 xv0 = *reinterpret_cast<const float4*>(xr + g * 8);
    float4 xv1 = *reinterpret_cast<const float4*>(xr + g * 8 + 4);
    float4 xv2 = *reinterpret_cast<const float4*>(xr + 32 + g * 8);
    float4 xv3 = *reinterpret_cast<const float4*>(xr + 32 + g * 8 + 4);
    float  alv = alpha[tid];          // N_IND == blockDim.x

    // ---- (3) per-thread staging weights: cols gr*8 .. gr*8+7 ----
    const int gr = tid & 7;           // granule column-group (fixed per thread)
    const int row_base = tid >> 3;    // row = rb*128 + row_base
    float wz[8];
#pragma unroll
    for (int e = 0; e < 8; ++e) wz[e] = __expf(-0.5f * ls[gr * 8 + e]);

    // ---- (2) z staging: 8 granules, 2-deep pipelined, swizzled dest ----
    char* zbw = reinterpret_cast<char*>(sm.zt);

#define ZLD(rb, A, B)                                                          \
    {                                                                          \
        const float* zp_ = z + (size_t)((rb) * 128 + row_base) * 64 + gr * 8;  \
        A = *reinterpret_cast<const float4*>(zp_);                             \
        B = *reinterpret_cast<const float4*>(zp_ + 4);                         \
    }
#define ZCVT(rb, A, B)                                                         \
    {                                                                          \
        float vv_[8] = {A.x, A.y, A.z, A.w, B.x, B.y, B.z, B.w};               \
        ushort hb_[8]; float sq_ = 0.f;                                        \
        _Pragma("unroll")                                                      \
        for (int e = 0; e < 8; ++e) {                                          \
            ushort h_ = f2bf(vv_[e] * wz[e]);                                  \
            hb_[e] = h_;                                                       \
            float vr_ = bf2f(h_);                                              \
            sq_ = fmaf(vr_, vr_, sq_);                                         \
        }                                                                      \
        uint4 u_ = make_uint4(                                                 \
            (unsigned)hb_[0] | ((unsigned)hb_[1] << 16),                       \
            (unsigned)hb_[2] | ((unsigned)hb_[3] << 16),                       \
            (unsigned)hb_[4] | ((unsigned)hb_[5] << 16),                       \
            (unsigned)hb_[6] | ((unsigned)hb_[7] << 16));                      \
        int row_ = (rb) * 128 + row_base;                                      \
        int sw_  = row_ * 128 + ((gr * 16) ^ ((row_ & 7) << 4));               \
        *reinterpret_cast<uint4*>(zbw + sw_) = u_;                             \
        sq_ += __shfl_xor(sq_, 1);                                             \
        sq_ += __shfl_xor(sq_, 2);                                             \
        sq_ += __shfl_xor(sq_, 4);                                             \
        if (gr == 0) sm.z2[row_] = sq_ * L2E;                                  \
    }

    float4 cA, cB, nA, nB;
    ZLD(0, cA, cB)
    ZLD(1, nA, nB)
    ZCVT(0, cA, cB)  ZLD(2, cA, cB)
    ZCVT(1, nA, nB)  ZLD(3, nA, nB)
    ZCVT(2, cA, cB)  ZLD(4, cA, cB)
    ZCVT(3, nA, nB)  ZLD(5, nA, nB)
    ZCVT(4, cA, cB)  ZLD(6, cA, cB)
    ZCVT(5, nA, nB)  ZLD(7, nA, nB)
    ZCVT(6, cA, cB)
    ZCVT(7, nA, nB)
#undef ZLD
#undef ZCVT

    sm.al[tid] = alv;

    // ---- convert x (loads long in flight) + xs2; then barrier ----
    short8 b0, b1;
    float xs2;
    {
        float wx[16];
#pragma unroll
        for (int h = 0; h < 2; ++h)
#pragma unroll
            for (int e = 0; e < 8; ++e)
                wx[h * 8 + e] = __expf(-0.5f * ls[h * 32 + g * 8 + e]);
        float vv[16] = {xv0.x, xv0.y, xv0.z, xv0.w, xv1.x, xv1.y, xv1.z, xv1.w,
                        xv2.x, xv2.y, xv2.z, xv2.w, xv3.x, xv3.y, xv3.z, xv3.w};
        float sq = 0.f;
        short8 bb[2];
#pragma unroll
        for (int h = 0; h < 2; ++h)
#pragma unroll
            for (int e = 0; e < 8; ++e) {
                ushort hh = f2bf(vv[h * 8 + e] * wx[h * 8 + e]);
                bb[h][e] = (short)hh;
                float xv = bf2f(hh);
                sq = fmaf(xv, xv, sq);
            }
        b0 = bb[0]; b1 = bb[1];
        sq += __shfl_xor(sq, 16);
        sq += __shfl_xor(sq, 32);
        xs2 = sq * L2E;
    }

    __syncthreads();   // z-panel + z2 + al ready (LDS read-only from here)

    const char* zb = reinterpret_cast<const char*>(sm.zt);
    const int rb0 = p * 128 + ((16 * g)      ^ ((p & 7) << 4));
    const int rb1 = p * 128 + ((64 + 16 * g) ^ ((p & 7) << 4));

    f32x2 accJ = {0.f, 0.f};
    const f32x2 xs2p = {xs2, xs2};

#pragma unroll 2
    for (int it = 0; it < TILES; ++it) {
        short8 a0 = *reinterpret_cast<const short8*>(zb + it * 2048 + rb0);
        short8 a1 = *reinterpret_cast<const short8*>(zb + it * 2048 + rb1);
        float4 z2 = *reinterpret_cast<const float4*>(&sm.z2[it * 16 + g * 4]);

        f32x4 t = {0.f, 0.f, 0.f, 0.f};
        t = __builtin_amdgcn_mfma_f32_16x16x32_bf16(a0, b0, t, 0, 0, 0);
        t = __builtin_amdgcn_mfma_f32_16x16x32_bf16(a1, b1, t, 0, 0, 0);

        f32x2 z2p0 = {z2.x, z2.y}, z2p1 = {z2.z, z2.w};
        f32x2 d0 = {t[0], t[1]}, d1 = {t[2], t[3]};
        f32x2 arg0 = d0 * L2E2 - (z2p0 + xs2p);    // pk_fma / pk_add
        f32x2 arg1 = d1 * L2E2 - (z2p1 + xs2p);
        float m = fmaxf(fmaxf(arg0.x, arg0.y), fmaxf(arg1.x, arg1.y));

        if (!__all(m < SKIP_THR)) {
            // rare path: a real contribution exists somewhere in this tile
            float4 a4 = *reinterpret_cast<const float4*>(&sm.al[it * 16 + g * 4]);
            f32x2 pv0 = {__builtin_amdgcn_exp2f(arg0.x),
                         __builtin_amdgcn_exp2f(arg0.y)};
            f32x2 pv1 = {__builtin_amdgcn_exp2f(arg1.x),
                         __builtin_amdgcn_exp2f(arg1.y)};
            f32x2 a4p0 = {a4.x, a4.y}, a4p1 = {a4.z, a4.w};
            accJ = accJ + a4p0 * pv0;              // pk_fma
            accJ = accJ + a4p1 * pv1;              // pk_fma
        }
    }

    float r = accJ.x + accJ.y;
    r += __shfl_xor(r, 16);
    r += __shfl_xor(r, 32);
    if (g == 0) out[j] = r;
}

extern "C" void kernel_launch(void* const* d_in, const int* in_sizes, int n_in,
                              void* d_out, int out_size, void* d_ws, size_t ws_size,
                              hipStream_t stream) {
    const float* x     = (const float*)d_in[0];   // (65536, 64)
    const float* z     = (const float*)d_in[1];   // (1024, 64)
    const float* alpha = (const float*)d_in[2];   // (1024,)
    const float* ls    = (const float*)d_in[3];   // (64,)
    float* out = (float*)d_out;                   // (65536, 1)

    igpr_fused<<<dim3(N_X / 256), dim3(1024), 0, stream>>>(x, z, alpha, ls, out);
}

// Round 15
// 20.249 us; speedup vs baseline: 4.5692x; 1.0882x over previous
//
#include <hip/hip_runtime.h>
#include <hip/hip_bf16.h>

#define N_X    65536
#define N_IND  1024
#define N_DESC 64
#define TILES  (N_IND / 16)       // 64 MFMA row-tiles (full z-panel)
#define L2E    1.4426950408889634f
#define L2E2   2.8853900817779268f
#define SKIP_THR (-60.0f)         // 2^-60 * 1024 * |alpha| ~ 4e-15 << tol

typedef __attribute__((ext_vector_type(8))) short  short8;
typedef __attribute__((ext_vector_type(4))) float  f32x4;
typedef __attribute__((ext_vector_type(2))) float  f32x2;

static __device__ __forceinline__ ushort f2bf(float f) {
    union { float f; unsigned u; } a; a.f = f;
    unsigned r = a.u + 0x7FFF + ((a.u >> 16) & 1);   // RNE to bf16
    return (ushort)(r >> 16);
}
static __device__ __forceinline__ float bf2f(ushort h) {
    union { unsigned u; float f; } a; a.u = (unsigned)h << 16;
    return a.f;
}

// ---------------------------------------------------------------------------
// Round 15 = R14 + z2 off the common path. The loop is LDS-issue-bound
// (3 b128/tile ~ 41 cyc); the z2 b128 only feeds the arg that the (always-
// taken) skip test discards. Replace with per-tile bound z2m[t] = min z2
// over the tile's 16 rows (precomputed once, 2 barriers): common path =
// 2 swizzled A b128 + 1 broadcast b32 (z2m) + 2 MFMA + ~6 VALU:
//   skip iff  L2E2*max(t[0..3]) - z2m[it] - xs2 < -60   for all 64 lanes
// (sound: min z2 over tile bounds every row's z2; slack ~300 << margin
// ~1800). Kept path (never taken in practice) reads z2+alpha float4 and
// reproduces R12's exact math. unroll 4 for denser LDS issue.
// Staging/prologue identical to R14 (pipelined, early x-loads, no wls LDS).
// Swizzle: byte colb ^= (row&7)<<4 on BOTH write and read (rule #21).
// C/D: col = lane&15 (x-col), row = 4*(lane>>4)+reg (z-row).
// ---------------------------------------------------------------------------
__global__ __launch_bounds__(1024) void igpr_fused(
        const float* __restrict__ x, const float* __restrict__ z,
        const float* __restrict__ alpha, const float* __restrict__ ls,
        float* __restrict__ out) {
    struct SM {
        uint4 zt[N_IND * 8];   // 1024 rows * 128 B = 128 KB (swizzled)
        float z2[N_IND];       // log2e * ||zw_i||^2
        float al[N_IND];       // alpha
        float z2m[TILES];      // per-tile min of z2 (skip bound)
    };
    __shared__ SM sm;          // ~136.3 KB of the CU's 160 KB

    const int tid  = threadIdx.x;
    const int lane = tid & 63;
    const int wave = tid >> 6;
    const int p = lane & 15;          // x-col within strip / D col
    const int g = lane >> 4;          // k-group; D rows 4g..4g+3 (z-rows)
    const int j = blockIdx.x * 256 + wave * 16 + p;   // this lane's x column

    // ---- issue x loads immediately; consumed after z staging ----
    const float* xr = x + (size_t)j * N_DESC;
    float4 xv0 = *reinterpret_cast<const float4*>(xr + g * 8);
    float4 xv1 = *reinterpret_cast<const float4*>(xr + g * 8 + 4);
    float4 xv2 = *reinterpret_cast<const float4*>(xr + 32 + g * 8);
    float4 xv3 = *reinterpret_cast<const float4*>(xr + 32 + g * 8 + 4);
    float  alv = alpha[tid];          // N_IND == blockDim.x

    // ---- per-thread staging weights: cols gr*8 .. gr*8+7 ----
    const int gr = tid & 7;           // granule column-group (fixed per thread)
    const int row_base = tid >> 3;    // row = rb*128 + row_base
    float wz[8];
#pragma unroll
    for (int e = 0; e < 8; ++e) wz[e] = __expf(-0.5f * ls[gr * 8 + e]);

    // ---- z staging: 8 granules, 2-deep pipelined, swizzled dest ----
    char* zbw = reinterpret_cast<char*>(sm.zt);

#define ZLD(rb, A, B)                                                          \
    {                                                                          \
        const float* zp_ = z + (size_t)((rb) * 128 + row_base) * 64 + gr * 8;  \
        A = *reinterpret_cast<const float4*>(zp_);                             \
        B = *reinterpret_cast<const float4*>(zp_ + 4);                         \
    }
#define ZCVT(rb, A, B)                                                         \
    {                                                                          \
        float vv_[8] = {A.x, A.y, A.z, A.w, B.x, B.y, B.z, B.w};               \
        ushort hb_[8]; float sq_ = 0.f;                                        \
        _Pragma("unroll")                                                      \
        for (int e = 0; e < 8; ++e) {                                          \
            ushort h_ = f2bf(vv_[e] * wz[e]);                                  \
            hb_[e] = h_;                                                       \
            float vr_ = bf2f(h_);                                              \
            sq_ = fmaf(vr_, vr_, sq_);                                         \
        }                                                                      \
        uint4 u_ = make_uint4(                                                 \
            (unsigned)hb_[0] | ((unsigned)hb_[1] << 16),                       \
            (unsigned)hb_[2] | ((unsigned)hb_[3] << 16),                       \
            (unsigned)hb_[4] | ((unsigned)hb_[5] << 16),                       \
            (unsigned)hb_[6] | ((unsigned)hb_[7] << 16));                      \
        int row_ = (rb) * 128 + row_base;                                      \
        int sw_  = row_ * 128 + ((gr * 16) ^ ((row_ & 7) << 4));               \
        *reinterpret_cast<uint4*>(zbw + sw_) = u_;                             \
        sq_ += __shfl_xor(sq_, 1);                                             \
        sq_ += __shfl_xor(sq_, 2);                                             \
        sq_ += __shfl_xor(sq_, 4);                                             \
        if (gr == 0) sm.z2[row_] = sq_ * L2E;                                  \
    }

    float4 cA, cB, nA, nB;
    ZLD(0, cA, cB)
    ZLD(1, nA, nB)
    ZCVT(0, cA, cB)  ZLD(2, cA, cB)
    ZCVT(1, nA, nB)  ZLD(3, nA, nB)
    ZCVT(2, cA, cB)  ZLD(4, cA, cB)
    ZCVT(3, nA, nB)  ZLD(5, nA, nB)
    ZCVT(4, cA, cB)  ZLD(6, cA, cB)
    ZCVT(5, nA, nB)  ZLD(7, nA, nB)
    ZCVT(6, cA, cB)
    ZCVT(7, nA, nB)
#undef ZLD
#undef ZCVT

    sm.al[tid] = alv;

    // ---- convert x (loads long in flight) + xs2 ----
    short8 b0, b1;
    float xs2;
    {
        float wx[16];
#pragma unroll
        for (int h = 0; h < 2; ++h)
#pragma unroll
            for (int e = 0; e < 8; ++e)
                wx[h * 8 + e] = __expf(-0.5f * ls[h * 32 + g * 8 + e]);
        float vv[16] = {xv0.x, xv0.y, xv0.z, xv0.w, xv1.x, xv1.y, xv1.z, xv1.w,
                        xv2.x, xv2.y, xv2.z, xv2.w, xv3.x, xv3.y, xv3.z, xv3.w};
        float sq = 0.f;
        short8 bb[2];
#pragma unroll
        for (int h = 0; h < 2; ++h)
#pragma unroll
            for (int e = 0; e < 8; ++e) {
                ushort hh = f2bf(vv[h * 8 + e] * wx[h * 8 + e]);
                bb[h][e] = (short)hh;
                float xv = bf2f(hh);
                sq = fmaf(xv, xv, sq);
            }
        b0 = bb[0]; b1 = bb[1];
        sq += __shfl_xor(sq, 16);
        sq += __shfl_xor(sq, 32);
        xs2 = sq * L2E;
    }

    __syncthreads();   // z2 complete

    // ---- per-tile skip bound: z2m[t] = min z2 over the tile's 16 rows ----
    if (tid < TILES) {
        float mn = sm.z2[tid * 16];
#pragma unroll
        for (int i = 1; i < 16; ++i) mn = fminf(mn, sm.z2[tid * 16 + i]);
        sm.z2m[tid] = mn;
    }

    __syncthreads();   // z-panel + z2 + z2m + al ready (read-only from here)

    const char* zb = reinterpret_cast<const char*>(sm.zt);
    const int rb0 = p * 128 + ((16 * g)      ^ ((p & 7) << 4));
    const int rb1 = p * 128 + ((64 + 16 * g) ^ ((p & 7) << 4));

    f32x2 accJ = {0.f, 0.f};
    const f32x2 xs2p = {xs2, xs2};
    const float thr_base = SKIP_THR + xs2;   // test: L2E2*maxdot - z2m < thr_base

#pragma unroll 4
    for (int it = 0; it < TILES; ++it) {
        short8 a0 = *reinterpret_cast<const short8*>(zb + it * 2048 + rb0);
        short8 a1 = *reinterpret_cast<const short8*>(zb + it * 2048 + rb1);
        float zm = sm.z2m[it];               // wave-uniform b32 broadcast

        f32x4 t = {0.f, 0.f, 0.f, 0.f};
        t = __builtin_amdgcn_mfma_f32_16x16x32_bf16(a0, b0, t, 0, 0, 0);
        t = __builtin_amdgcn_mfma_f32_16x16x32_bf16(a1, b1, t, 0, 0, 0);

        float maxdot = fmaxf(fmaxf(t[0], t[1]), fmaxf(t[2], t[3]));
        float bound  = fmaf(maxdot, L2E2, -zm);   // >= every lane's arg + xs2

        if (!__all(bound < thr_base)) {
            // rare path: a real contribution may exist in this tile
            float4 z2 = *reinterpret_cast<const float4*>(&sm.z2[it * 16 + g * 4]);
            float4 a4 = *reinterpret_cast<const float4*>(&sm.al[it * 16 + g * 4]);
            f32x2 z2p0 = {z2.x, z2.y}, z2p1 = {z2.z, z2.w};
            f32x2 d0 = {t[0], t[1]}, d1 = {t[2], t[3]};
            f32x2 arg0 = d0 * L2E2 - (z2p0 + xs2p);
            f32x2 arg1 = d1 * L2E2 - (z2p1 + xs2p);
            f32x2 pv0 = {__builtin_amdgcn_exp2f(arg0.x),
                         __builtin_amdgcn_exp2f(arg0.y)};
            f32x2 pv1 = {__builtin_amdgcn_exp2f(arg1.x),
                         __builtin_amdgcn_exp2f(arg1.y)};
            f32x2 a4p0 = {a4.x, a4.y}, a4p1 = {a4.z, a4.w};
            accJ = accJ + a4p0 * pv0;              // pk_fma
            accJ = accJ + a4p1 * pv1;              // pk_fma
        }
    }

    float r = accJ.x + accJ.y;
    r += __shfl_xor(r, 16);
    r += __shfl_xor(r, 32);
    if (g == 0) out[j] = r;
}

extern "C" void kernel_launch(void* const* d_in, const int* in_sizes, int n_in,
                              void* d_out, int out_size, void* d_ws, size_t ws_size,
                              hipStream_t stream) {
    const float* x     = (const float*)d_in[0];   // (65536, 64)
    const float* z     = (const float*)d_in[1];   // (1024, 64)
    const float* alpha = (const float*)d_in[2];   // (1024,)
    const float* ls    = (const float*)d_in[3];   // (64,)
    float* out = (float*)d_out;                   // (65536, 1)

    igpr_fused<<<dim3(N_X / 256), dim3(1024), 0, stream>>>(x, z, alpha, ls, out);
}